// Round 1
// baseline (618.019 us; speedup 1.0000x reference)
//
#include <hip/hip_runtime.h>

// LittleBitITQSpecLinear: y = sum_b ((x*v2_b) @ sign(V_b)^T * (v1_b*u2_b)) @ sign(U_b)^T * u1_b + bias
// Folded: W1_b[s,k] = sign(V_b[s,k])*v2_b[k];  W2_b[o,s] = sign(U_b[o,s])*v1_b[s]*u2_b[s]*u1_b[o]
// => H = Xbf16 @ W1cat^T  (8192x2048, K=4096);  Y = H @ W2cat^T + bias (8192x4096, K=2048)
//
// R3: replace the m97 128^2 2-barrier GEMM (ceiling ~980 TF, drain-per-K-step)
// with the 256^2 8-wave phase-split schedule: counted vmcnt (never a cold
// drain at a tile boundary), raw s_barrier (no compiler vmcnt(0)+lgkmcnt(0)
// drain), setprio around MFMA clusters, reg-level one-phase-ahead fragment
// prefetch, XCD-aware block swizzle. LDS keeps the proven fetch-side chunk-XOR
// swizzle (0 bank conflicts measured) with linear global_load_lds dests.

typedef __bf16 bf16x8 __attribute__((ext_vector_type(8)));
typedef float floatx4 __attribute__((ext_vector_type(4)));

__device__ __forceinline__ unsigned short f2bf_rne(float f) {
    union { float f; unsigned u; } v; v.f = f;
    unsigned r = v.u + 0x7FFFu + ((v.u >> 16) & 1u);
    return (unsigned short)(r >> 16);
}

__device__ __forceinline__ float sgnf(float w) {
    return (float)((w > 0.f) - (w < 0.f));
}

__device__ __forceinline__ void async_copy16(const void* g, void* l) {
    __builtin_amdgcn_global_load_lds(
        (const __attribute__((address_space(1))) void*)g,
        (__attribute__((address_space(3))) void*)l, 16, 0, 0);
}

#define FENCE() asm volatile("" ::: "memory")
#define BAR() do { FENCE(); __builtin_amdgcn_s_barrier(); FENCE(); } while (0)
#define VMW(N) asm volatile("s_waitcnt vmcnt(" #N ")" ::: "memory")

// ---------------- prep kernels (unchanged, proven) ----------------

__global__ void cast_x_kernel(const float* __restrict__ x,
                              unsigned short* __restrict__ xb, int n4) {
    int i = blockIdx.x * blockDim.x + threadIdx.x;
    if (i >= n4) return;
    float4 v = ((const float4*)x)[i];
    ushort4 o;
    o.x = f2bf_rne(v.x); o.y = f2bf_rne(v.y);
    o.z = f2bf_rne(v.z); o.w = f2bf_rne(v.w);
    ((ushort4*)xb)[i] = o;
}

// Fused weight prep. Blocks [0,8192): W1cat[s_cat][k] (2048x4096).
// Blocks [8192,16384): W2cat[o][s_cat] (4096x2048).
__global__ void prep_w_kernel(const float* __restrict__ V, const float* __restrict__ V_R,
                              const float* __restrict__ v2, const float* __restrict__ v2_R,
                              const float* __restrict__ U, const float* __restrict__ U_R,
                              const float* __restrict__ v1, const float* __restrict__ v1_R,
                              const float* __restrict__ u2, const float* __restrict__ u2_R,
                              const float* __restrict__ u1, const float* __restrict__ u1_R,
                              unsigned short* __restrict__ W1,
                              unsigned short* __restrict__ W2) {
    int bid = blockIdx.x;
    if (bid < 8192) {
        int i = bid * blockDim.x + threadIdx.x;  // 4 elems each
        int idx = i << 2;
        int scat = idx >> 12;
        int k = idx & 4095;
        const float* Vp; const float* sp;
        if (scat < 1024) { Vp = V + ((size_t)scat << 12); sp = v2; }
        else             { Vp = V_R + ((size_t)(scat - 1024) << 12); sp = v2_R; }
        float4 w = *(const float4*)(Vp + k);
        float4 s = *(const float4*)(sp + k);
        ushort4 o;
        o.x = f2bf_rne(sgnf(w.x) * s.x);
        o.y = f2bf_rne(sgnf(w.y) * s.y);
        o.z = f2bf_rne(sgnf(w.z) * s.z);
        o.w = f2bf_rne(sgnf(w.w) * s.w);
        ((ushort4*)W1)[i] = o;
    } else {
        int i = (bid - 8192) * blockDim.x + threadIdx.x;  // 4 elems each
        int idx = i << 2;
        int o = idx >> 11;
        int scat = idx & 2047;
        int branch = scat >> 10;
        int s = scat & 1023;
        const float* Up  = branch ? U_R  : U;
        const float* v1p = branch ? v1_R : v1;
        const float* u2p = branch ? u2_R : u2;
        float u1v = (branch ? u1_R : u1)[o];
        float4 w = *(const float4*)(Up + ((size_t)o << 10) + s);
        float4 a = *(const float4*)(v1p + s);
        float4 b = *(const float4*)(u2p + s);
        ushort4 out;
        out.x = f2bf_rne(sgnf(w.x) * a.x * b.x * u1v);
        out.y = f2bf_rne(sgnf(w.y) * a.y * b.y * u1v);
        out.z = f2bf_rne(sgnf(w.z) * a.z * b.z * u1v);
        out.w = f2bf_rne(sgnf(w.w) * a.w * b.w * u1v);
        ((ushort4*)W2)[i] = out;
    }
}

// ---------------- GEMM: C[M,N] = A[M,K] @ B[N,K]^T ----------------
// 256x256 tile, BK=64, 512 threads = 8 waves (2M x 4N), per-wave 128x64 out.
// Phases per K-tile (quadrants Q1..Q4 of the per-wave tile):
//   ph1: stage 6 blocks of t+1 {A0,A2,B0..B3}; ds_read B-nh1(t); MFMA Q1(a0,b0)
//        VMW(6)  <- retires only prev iter's {A1,A3} (tile t's) ; BAR
//   ph2: ds_read A-mh1(t); MFMA Q2(a0,b1); VMW(0) <- t+1's 6 blocks, >=1 phase
//        of cover since issue; BAR
//   ph3: MFMA Q3(a1,b1)                      (no barrier)
//   ph4: stage 2 blocks of t+1 {A1,A3}; ds_read a0/b0 of t+1 from other buf
//        (disjoint blocks from the in-flight {A1,A3} writes); MFMA Q4(a1,b0); BAR
// Loads crossing the iteration boundary: exactly {A1,A3} -> pipeline never
// fully drains at a tile boundary.

template <bool OUT_BF16, bool ADD_BIAS>
__global__ __launch_bounds__(512, 2)
void gemm256(const unsigned short* __restrict__ A,
             const unsigned short* __restrict__ B,
             void* __restrict__ Cv,
             const float* __restrict__ bias,
             int M, int N, int K, int ntn) {
    (void)M;
    __shared__ __align__(16) unsigned short As[2][256 * 64];
    __shared__ __align__(16) unsigned short Bs[2][256 * 64];

    const int tid = threadIdx.x;
    const int lane = tid & 63;
    const int wave = tid >> 6;
    const int warp_m = wave >> 2;   // 0..1
    const int warp_n = wave & 3;    // 0..3

    // XCD-aware swizzle (nwg % 8 == 0 for both GEMMs -> bijective)
    const int nwg = gridDim.x;
    const int hw = blockIdx.x;
    const int swz = (hw & 7) * (nwg >> 3) + (hw >> 3);
    const int tm = swz / ntn;
    const int tn = swz - tm * ntn;
    const int m0 = tm << 8;
    const int n0 = tn << 8;

    // staging: 512 threads stage one 64-row block per global_load_lds instr.
    // Fetch-side XOR swizzle: LDS[r][c] = global[r][c ^ (r&7)], dest linear.
    const int srow = tid >> 3;                          // 0..63
    const int scg8 = (((tid & 7) ^ (srow & 7)) << 3);   // swizzled chunk * 8
    const size_t aTB = (size_t)(m0 + srow) * (size_t)K + scg8;
    const size_t bTB = (size_t)(n0 + srow) * (size_t)K + scg8;
    const int ldst = tid << 3;                          // elems

    auto stageA = [&](int buf, int blk, int kt) {
        async_copy16(A + aTB + ((size_t)(blk << 6)) * (size_t)K + (kt << 6),
                     &As[buf][(blk << 12) + ldst]);
    };
    auto stageB = [&](int buf, int blk, int kt) {
        async_copy16(B + bTB + ((size_t)(blk << 6)) * (size_t)K + (kt << 6),
                     &Bs[buf][(blk << 12) + ldst]);
    };

    // fragment reads (read-side swizzle matches fetch-side)
    const int fm = lane & 15;
    const int cgl = lane >> 4;                // 0..3
    const int key = fm & 7;
    const int ok0 = ((cgl ^ key) << 3);       // elem offset, k-slice 0
    const int ok1 = (((4 | cgl) ^ key) << 3); // elem offset, k-slice 1
    const int arow0 = (warp_m << 7) + fm;
    const int brow0 = (warp_n << 6) + fm;

    auto lda = [&](bf16x8 (&dst)[4][2], int c, int mh) {
#pragma unroll
        for (int mi = 0; mi < 4; ++mi) {
            const unsigned short* p = &As[c][(arow0 + (mh << 6) + (mi << 4)) << 6];
            dst[mi][0] = *(const bf16x8*)(p + ok0);
            dst[mi][1] = *(const bf16x8*)(p + ok1);
        }
    };
    auto ldb = [&](bf16x8 (&dst)[2][2], int c, int nh) {
#pragma unroll
        for (int ni = 0; ni < 2; ++ni) {
            const unsigned short* p = &Bs[c][(brow0 + (nh << 5) + (ni << 4)) << 6];
            dst[ni][0] = *(const bf16x8*)(p + ok0);
            dst[ni][1] = *(const bf16x8*)(p + ok1);
        }
    };

    floatx4 acc[8][4];
#pragma unroll
    for (int i = 0; i < 8; ++i)
#pragma unroll
        for (int j = 0; j < 4; ++j)
#pragma unroll
            for (int r = 0; r < 4; ++r) acc[i][j][r] = 0.f;

    bf16x8 a0[4][2], a1[4][2], b0[2][2], b1[2][2];

// MH/NH must be literals -> fully static acc indexing (no scratch).
#define MMAQ(aS, bS, MH, NH) do { \
    __builtin_amdgcn_s_setprio(1); \
    _Pragma("unroll") \
    for (int mi_ = 0; mi_ < 4; ++mi_) { \
      _Pragma("unroll") \
      for (int ni_ = 0; ni_ < 2; ++ni_) { \
        acc[(MH)*4 + mi_][(NH)*2 + ni_] = __builtin_amdgcn_mfma_f32_16x16x32_bf16( \
            aS[mi_][0], bS[ni_][0], acc[(MH)*4 + mi_][(NH)*2 + ni_], 0, 0, 0); \
        acc[(MH)*4 + mi_][(NH)*2 + ni_] = __builtin_amdgcn_mfma_f32_16x16x32_bf16( \
            aS[mi_][1], bS[ni_][1], acc[(MH)*4 + mi_][(NH)*2 + ni_], 0, 0, 0); \
      } } \
    __builtin_amdgcn_s_setprio(0); \
  } while (0)

    // prologue: full tile 0 into buf 0, drain, read Q1 operands
#pragma unroll
    for (int blk = 0; blk < 4; ++blk) stageA(0, blk, 0);
#pragma unroll
    for (int blk = 0; blk < 4; ++blk) stageB(0, blk, 0);
    VMW(0);
    BAR();
    lda(a0, 0, 0);
    ldb(b0, 0, 0);

    const int NT = K >> 6;
    for (int t = 0; t < NT - 1; ++t) {
        const int c = t & 1, nc = c ^ 1;
        // ---- phase 1: MFMA Q1 = (mh0, nh0) ----
        stageA(nc, 0, t + 1); stageA(nc, 2, t + 1);
        stageB(nc, 0, t + 1); stageB(nc, 1, t + 1);
        stageB(nc, 2, t + 1); stageB(nc, 3, t + 1);
        ldb(b1, c, 1);
        MMAQ(a0, b0, 0, 0);
        VMW(6);          // retire prev iter's {A1,A3} of tile t (buf c)
        BAR();
        // ---- phase 2: MFMA Q2 = (mh0, nh1) ----
        lda(a1, c, 1);
        MMAQ(a0, b1, 0, 1);
        VMW(0);          // retire t+1's {A0,A2,B0..B3} (buf nc)
        BAR();
        // ---- phase 3: MFMA Q3 = (mh1, nh1) ----
        MMAQ(a1, b1, 1, 1);
        // ---- phase 4: MFMA Q4 = (mh1, nh0); cross-tile reads ----
        stageA(nc, 1, t + 1); stageA(nc, 3, t + 1);   // in flight across BAR
        bf16x8 a0n[4][2], b0n[2][2];
        lda(a0n, nc, 0);   // blocks A0/A2 of t+1: landed (VMW(0)+BAR above)
        ldb(b0n, nc, 0);   // block B[warp_n] of t+1: landed
        MMAQ(a1, b0, 1, 0);
        BAR();
#pragma unroll
        for (int mi = 0; mi < 4; ++mi) { a0[mi][0] = a0n[mi][0]; a0[mi][1] = a0n[mi][1]; }
#pragma unroll
        for (int ni = 0; ni < 2; ++ni) { b0[ni][0] = b0n[ni][0]; b0[ni][1] = b0n[ni][1]; }
    }
    // epilogue: last tile, no prefetch
    {
        const int c = (NT - 1) & 1;
        ldb(b1, c, 1);
        MMAQ(a0, b0, 0, 0);
        VMW(0);          // retire {A1,A3} of last tile (staged at final ph4)
        BAR();
        lda(a1, c, 1);
        MMAQ(a0, b1, 0, 1);
        MMAQ(a1, b1, 1, 1);
        MMAQ(a1, b0, 1, 0);
    }
#undef MMAQ

    // epilogue C-write: C/D layout col=lane&15, row=(lane>>4)*4+reg [m89]
    const int rq = (lane >> 4) << 2;
    const int col = lane & 15;
#pragma unroll
    for (int mi = 0; mi < 8; ++mi) {
#pragma unroll
        for (int r = 0; r < 4; ++r) {
            const int gm = m0 + (warp_m << 7) + (mi << 4) + rq + r;
            const size_t base = (size_t)gm * (size_t)N;
#pragma unroll
            for (int ni = 0; ni < 4; ++ni) {
                const int gn = n0 + (warp_n << 6) + (ni << 4) + col;
                float v = acc[mi][ni][r];
                if (ADD_BIAS) v += bias[gn];
                if (OUT_BF16)
                    ((unsigned short*)Cv)[base + gn] = f2bf_rne(v);
                else
                    ((float*)Cv)[base + gn] = v;
            }
        }
    }
}

// ---------------- launch ----------------

extern "C" void kernel_launch(void* const* d_in, const int* in_sizes, int n_in,
                              void* d_out, int out_size, void* d_ws, size_t ws_size,
                              hipStream_t stream) {
    const float* x    = (const float*)d_in[0];
    const float* V    = (const float*)d_in[1];
    const float* U    = (const float*)d_in[2];
    const float* v2   = (const float*)d_in[3];
    const float* v1   = (const float*)d_in[4];
    const float* u2   = (const float*)d_in[5];
    const float* u1   = (const float*)d_in[6];
    const float* V_R  = (const float*)d_in[7];
    const float* U_R  = (const float*)d_in[8];
    const float* v2_R = (const float*)d_in[9];
    const float* v1_R = (const float*)d_in[10];
    const float* u2_R = (const float*)d_in[11];
    const float* u1_R = (const float*)d_in[12];
    const float* bias = (const float*)d_in[13];
    float* out = (float*)d_out;

    char* ws = (char*)d_ws;
    unsigned short* Xb = (unsigned short*)ws;                                   // 8192*4096*2 = 64 MiB
    unsigned short* W1 = (unsigned short*)(ws + (size_t)67108864);              // 2048*4096*2 = 16 MiB
    unsigned short* W2 = (unsigned short*)(ws + (size_t)67108864 + 16777216);   // 4096*2048*2 = 16 MiB
    unsigned short* H  = (unsigned short*)(ws + (size_t)67108864 + 33554432);   // 8192*2048*2 = 32 MiB

    // x: 8192*4096 = 33554432 floats -> /4 = 8388608 threads
    cast_x_kernel<<<32768, 256, 0, stream>>>(x, Xb, 8388608);
    // fused weight prep: 8192 blocks W1 + 8192 blocks W2
    prep_w_kernel<<<16384, 256, 0, stream>>>(V, V_R, v2, v2_R,
                                             U, U_R, v1, v1_R, u2, u2_R, u1, u1_R,
                                             W1, W2);

    // GEMM1: H[8192,2048] = Xb @ W1^T, K=4096  -> 32x8 = 256 tiles
    gemm256<true, false><<<dim3(256), 512, 0, stream>>>(Xb, W1, (void*)H, nullptr,
                                                        8192, 2048, 4096, 8);
    // GEMM2: Y[8192,4096] = H @ W2^T + bias, K=2048 -> 32x16 = 512 tiles
    gemm256<false, true><<<dim3(512), 512, 0, stream>>>(H, W2, (void*)out, bias,
                                                        8192, 4096, 2048, 16);
}

// Round 3
// 536.793 us; speedup vs baseline: 1.1513x; 1.1513x over previous
//
#include <hip/hip_runtime.h>

// LittleBitITQSpecLinear: y = sum_b ((x*v2_b) @ sign(V_b)^T * (v1_b*u2_b)) @ sign(U_b)^T * u1_b + bias
// Folded: W1_b[s,k] = sign(V_b[s,k])*v2_b[k];  W2_b[o,s] = sign(U_b[o,s])*v1_b[s]*u2_b[s]*u1_b[o]
// => H = Xbf16 @ W1cat^T  (8192x2048, K=4096);  Y = H @ W2cat^T + bias (8192x4096, K=2048)
//
// R5: race-free 8-phase counted-vmcnt schedule.
// R4 failed with non-deterministic absmax (468 / 0.035) -> race: staging t+2
// into the SAME buffer as the tile being read, in the SAME phase as reads of
// that region (read-issue vs write-land window). Fix: quadrant order
// Q00,Q01,Q11,Q10 with JIT reads (a0,b0@ph1, b1@ph2, a1@ph3) makes B regions
// dead after ph2 and A regions dead after ph3; stage t2.B@ph3, t2.A@ph4
// (t3.B@ph7, t3.A@ph8). Every LDS overwrite is issued after a barrier that
// follows the lgkmcnt(0) completing the last read of that region -> ordering
// guaranteed by barrier semantics, no probabilistic windows.
// vmcnt(8) at ph4 retires exactly tile t1 (8 loads) before ph5 reads it;
// vmcnt(8) at ph8 retires t2. Loads get 4-5 phases (~600-1000cy) of cover.
// Never a vmcnt(0) drain in the main loop.

typedef __bf16 bf16x8 __attribute__((ext_vector_type(8)));
typedef float floatx4 __attribute__((ext_vector_type(4)));

__device__ __forceinline__ unsigned short f2bf_rne(float f) {
    union { float f; unsigned u; } v; v.f = f;
    unsigned r = v.u + 0x7FFFu + ((v.u >> 16) & 1u);
    return (unsigned short)(r >> 16);
}

__device__ __forceinline__ float sgnf(float w) {
    return (float)((w > 0.f) - (w < 0.f));
}

__device__ __forceinline__ void async_copy16(const void* g, void* l) {
    __builtin_amdgcn_global_load_lds(
        (const __attribute__((address_space(1))) void*)g,
        (__attribute__((address_space(3))) void*)l, 16, 0, 0);
}

#define FENCE() asm volatile("" ::: "memory")
#define BAR() do { FENCE(); __builtin_amdgcn_s_barrier(); FENCE(); } while (0)
#define VMW(N) asm volatile("s_waitcnt vmcnt(" #N ")" ::: "memory")
#define LGKM(N) asm volatile("s_waitcnt lgkmcnt(" #N ")" ::: "memory")

// ---------------- prep kernels (unchanged, proven) ----------------

__global__ void cast_x_kernel(const float* __restrict__ x,
                              unsigned short* __restrict__ xb, int n4) {
    int i = blockIdx.x * blockDim.x + threadIdx.x;
    if (i >= n4) return;
    float4 v = ((const float4*)x)[i];
    ushort4 o;
    o.x = f2bf_rne(v.x); o.y = f2bf_rne(v.y);
    o.z = f2bf_rne(v.z); o.w = f2bf_rne(v.w);
    ((ushort4*)xb)[i] = o;
}

// Fused weight prep. Blocks [0,8192): W1cat[s_cat][k] (2048x4096).
// Blocks [8192,16384): W2cat[o][s_cat] (4096x2048).
__global__ void prep_w_kernel(const float* __restrict__ V, const float* __restrict__ V_R,
                              const float* __restrict__ v2, const float* __restrict__ v2_R,
                              const float* __restrict__ U, const float* __restrict__ U_R,
                              const float* __restrict__ v1, const float* __restrict__ v1_R,
                              const float* __restrict__ u2, const float* __restrict__ u2_R,
                              const float* __restrict__ u1, const float* __restrict__ u1_R,
                              unsigned short* __restrict__ W1,
                              unsigned short* __restrict__ W2) {
    int bid = blockIdx.x;
    if (bid < 8192) {
        int i = bid * blockDim.x + threadIdx.x;  // 4 elems each
        int idx = i << 2;
        int scat = idx >> 12;
        int k = idx & 4095;
        const float* Vp; const float* sp;
        if (scat < 1024) { Vp = V + ((size_t)scat << 12); sp = v2; }
        else             { Vp = V_R + ((size_t)(scat - 1024) << 12); sp = v2_R; }
        float4 w = *(const float4*)(Vp + k);
        float4 s = *(const float4*)(sp + k);
        ushort4 o;
        o.x = f2bf_rne(sgnf(w.x) * s.x);
        o.y = f2bf_rne(sgnf(w.y) * s.y);
        o.z = f2bf_rne(sgnf(w.z) * s.z);
        o.w = f2bf_rne(sgnf(w.w) * s.w);
        ((ushort4*)W1)[i] = o;
    } else {
        int i = (bid - 8192) * blockDim.x + threadIdx.x;  // 4 elems each
        int idx = i << 2;
        int o = idx >> 11;
        int scat = idx & 2047;
        int branch = scat >> 10;
        int s = scat & 1023;
        const float* Up  = branch ? U_R  : U;
        const float* v1p = branch ? v1_R : v1;
        const float* u2p = branch ? u2_R : u2;
        float u1v = (branch ? u1_R : u1)[o];
        float4 w = *(const float4*)(Up + ((size_t)o << 10) + s);
        float4 a = *(const float4*)(v1p + s);
        float4 b = *(const float4*)(u2p + s);
        ushort4 out;
        out.x = f2bf_rne(sgnf(w.x) * a.x * b.x * u1v);
        out.y = f2bf_rne(sgnf(w.y) * a.y * b.y * u1v);
        out.z = f2bf_rne(sgnf(w.z) * a.z * b.z * u1v);
        out.w = f2bf_rne(sgnf(w.w) * a.w * b.w * u1v);
        ((ushort4*)W2)[i] = out;
    }
}

// ---------------- GEMM: C[M,N] = A[M,K] @ B[N,K]^T ----------------
// 256x256 tile, BK=64, 512 threads = 8 waves (2M x 4N), per-wave 128x64 out.
// LDS: [buf][half] 128x64 bf16 = 16 KiB per region; 2 bufs x 2 halves x (A+B)
// = 128 KiB. Wave (wm,wn) reads A-half[wm] and B-half[wn>>1] only.

template <bool OUT_BF16, bool ADD_BIAS>
__global__ __launch_bounds__(512, 2)
void gemm256(const unsigned short* __restrict__ A,
             const unsigned short* __restrict__ B,
             void* __restrict__ Cv,
             const float* __restrict__ bias,
             int M, int N, int K, int ntn) {
    (void)M;
    __shared__ __align__(16) unsigned short As[2][2][128 * 64];
    __shared__ __align__(16) unsigned short Bs[2][2][128 * 64];

    const int tid = threadIdx.x;
    const int lane = tid & 63;
    const int wave = tid >> 6;
    const int warp_m = wave >> 2;   // 0..1
    const int warp_n = wave & 3;    // 0..3

    // XCD-aware swizzle (nwg % 8 == 0 for both GEMMs -> bijective)
    const int nwg = gridDim.x;
    const int hw = blockIdx.x;
    const int swz = (hw & 7) * (nwg >> 3) + (hw >> 3);
    const int tm = swz / ntn;
    const int tn = swz - tm * ntn;
    const int m0 = tm << 8;
    const int n0 = tn << 8;

    // staging: one half-tile region = 128 rows x 64 cols = 2 global_load_lds
    // (512 threads x 16B = 64 rows per instr). Fetch-side chunk-XOR swizzle:
    // LDS[r][c8] = global[r][c8 ^ (r&7)], LDS dest linear (HW requirement).
    const int srow = tid >> 3;                          // 0..63
    const int scg8 = (((tid & 7) ^ (srow & 7)) << 3);   // swizzled chunk * 8
    const int ldst = tid << 3;                          // 0..4095 elems
    const size_t Ks = (size_t)K;

    auto stA = [&](int buf, int h, int kt) {
        const unsigned short* g = A + (size_t)(m0 + (h << 7) + srow) * Ks + (kt << 6) + scg8;
        async_copy16(g,             &As[buf][h][ldst]);
        async_copy16(g + (Ks << 6), &As[buf][h][4096 + ldst]);
    };
    auto stB = [&](int buf, int h, int kt) {
        const unsigned short* g = B + (size_t)(n0 + (h << 7) + srow) * Ks + (kt << 6) + scg8;
        async_copy16(g,             &Bs[buf][h][ldst]);
        async_copy16(g + (Ks << 6), &Bs[buf][h][4096 + ldst]);
    };

    // fragment reads (read-side swizzle matches fetch-side; proven in R0)
    const int fm = lane & 15;
    const int cgl = lane >> 4;                // 0..3
    const int key = fm & 7;
    const int ok0 = ((cgl ^ key) << 3);       // elem offset, k-slice 0
    const int ok1 = (((4 | cgl) ^ key) << 3); // elem offset, k-slice 1

    auto lda = [&](bf16x8 (&dst)[4][2], int buf, int mh) {
        const unsigned short* base = &As[buf][warp_m][0];
#pragma unroll
        for (int mi = 0; mi < 4; ++mi) {
            const unsigned short* p = base + (((mh << 6) + (mi << 4) + fm) << 6);
            dst[mi][0] = *(const bf16x8*)(p + ok0);
            dst[mi][1] = *(const bf16x8*)(p + ok1);
        }
    };
    auto ldb = [&](bf16x8 (&dst)[2][2], int buf, int nh) {
        const unsigned short* base = &Bs[buf][warp_n >> 1][0];
#pragma unroll
        for (int ni = 0; ni < 2; ++ni) {
            const unsigned short* p = base + ((((warp_n & 1) << 6) + (nh << 5) + (ni << 4) + fm) << 6);
            dst[ni][0] = *(const bf16x8*)(p + ok0);
            dst[ni][1] = *(const bf16x8*)(p + ok1);
        }
    };

    floatx4 acc[8][4];
#pragma unroll
    for (int i = 0; i < 8; ++i)
#pragma unroll
        for (int j = 0; j < 4; ++j)
#pragma unroll
            for (int r = 0; r < 4; ++r) acc[i][j][r] = 0.f;

    bf16x8 a0[4][2], a1[4][2], b0[2][2], b1[2][2];

#define MMAQ(aS, bS, MH, NH) do { \
    __builtin_amdgcn_s_setprio(1); \
    _Pragma("unroll") \
    for (int mi_ = 0; mi_ < 4; ++mi_) { \
      _Pragma("unroll") \
      for (int ni_ = 0; ni_ < 2; ++ni_) { \
        acc[(MH)*4 + mi_][(NH)*2 + ni_] = __builtin_amdgcn_mfma_f32_16x16x32_bf16( \
            aS[mi_][0], bS[ni_][0], acc[(MH)*4 + mi_][(NH)*2 + ni_], 0, 0, 0); \
        acc[(MH)*4 + mi_][(NH)*2 + ni_] = __builtin_amdgcn_mfma_f32_16x16x32_bf16( \
            aS[mi_][1], bS[ni_][1], acc[(MH)*4 + mi_][(NH)*2 + ni_], 0, 0, 0); \
      } } \
    __builtin_amdgcn_s_setprio(0); \
  } while (0)

    // ---- prologue: tile0 (buf0, 8 loads) + tile1 (buf1, 8 loads);
    // VMW(8) retires tile0 -> resident; outstanding = tile1's 8 (invariant).
    stB(0, 0, 0); stB(0, 1, 0); stA(0, 0, 0); stA(0, 1, 0);
    stB(1, 0, 1); stB(1, 1, 1); stA(1, 0, 1); stA(1, 1, 1);
    VMW(8);
    BAR();

    const int NT = K >> 6;
    for (int i = 0; i < (NT >> 1) - 1; ++i) {
        const int t2k = 2 * i + 2, t3k = 2 * i + 3;
        // ph1: even tile (buf0) Q00
        lda(a0, 0, 0); ldb(b0, 0, 0);
        BAR(); LGKM(0);
        MMAQ(a0, b0, 0, 0);
        BAR();
        // ph2: Q01  (after this, buf0 B regions are dead)
        ldb(b1, 0, 1);
        BAR(); LGKM(0);
        MMAQ(a0, b1, 0, 1);
        BAR();
        // ph3: Q11; stage t2.B -> buf0 B regions (dead since ph2's lgkm+BAR)
        lda(a1, 0, 1);
        stB(0, 0, t2k); stB(0, 1, t2k);
        BAR(); LGKM(0);
        MMAQ(a1, b1, 1, 1);
        BAR();
        // ph4: Q10; stage t2.A -> buf0 A regions (dead since ph3's lgkm+BAR);
        // VMW(8): outstanding = t1(8)+t2(8) -> retires exactly t1.
        stA(0, 0, t2k); stA(0, 1, t2k);
        VMW(8);
        BAR();
        MMAQ(a1, b0, 1, 0);
        BAR();
        // ph5: odd tile (buf1) Q00
        lda(a0, 1, 0); ldb(b0, 1, 0);
        BAR(); LGKM(0);
        MMAQ(a0, b0, 0, 0);
        BAR();
        // ph6: Q01
        ldb(b1, 1, 1);
        BAR(); LGKM(0);
        MMAQ(a0, b1, 0, 1);
        BAR();
        // ph7: Q11; stage t3.B -> buf1 B regions (dead since ph6)
        lda(a1, 1, 1);
        stB(1, 0, t3k); stB(1, 1, t3k);
        BAR(); LGKM(0);
        MMAQ(a1, b1, 1, 1);
        BAR();
        // ph8: Q10; stage t3.A (buf1 A dead since ph7); VMW(8) retires t2.
        stA(1, 0, t3k); stA(1, 1, t3k);
        VMW(8);
        BAR();
        MMAQ(a1, b0, 1, 0);
        BAR();
    }
    // ---- epilogue: tiles NT-2 (buf0), NT-1 (buf1); outstanding = t(NT-1)'s 8.
    {
        lda(a0, 0, 0); ldb(b0, 0, 0);
        BAR(); LGKM(0);
        MMAQ(a0, b0, 0, 0);
        BAR();
        ldb(b1, 0, 1);
        BAR(); LGKM(0);
        MMAQ(a0, b1, 0, 1);
        BAR();
        lda(a1, 0, 1);
        BAR(); LGKM(0);
        MMAQ(a1, b1, 1, 1);
        BAR();
        VMW(0);          // retire t(NT-1) (issued 4+ phases ago; no real stall)
        BAR();
        MMAQ(a1, b0, 1, 0);
        BAR();
        // final tile NT-1 (buf1): fully resident; no further LDS writes.
        // Normal C++ ds_reads -> compiler inserts lgkm waits before MFMA use.
        lda(a0, 1, 0); ldb(b0, 1, 0);
        ldb(b1, 1, 1); lda(a1, 1, 1);
        MMAQ(a0, b0, 0, 0);
        MMAQ(a0, b1, 0, 1);
        MMAQ(a1, b1, 1, 1);
        MMAQ(a1, b0, 1, 0);
    }
#undef MMAQ

    // epilogue C-write: C/D layout col=lane&15, row=(lane>>4)*4+reg [m89]
    const int rq = (lane >> 4) << 2;
    const int col = lane & 15;
#pragma unroll
    for (int mi = 0; mi < 8; ++mi) {
#pragma unroll
        for (int r = 0; r < 4; ++r) {
            const int gm = m0 + (warp_m << 7) + (mi << 4) + rq + r;
            const size_t base = (size_t)gm * (size_t)N;
#pragma unroll
            for (int ni = 0; ni < 4; ++ni) {
                const int gn = n0 + (warp_n << 6) + (ni << 4) + col;
                float v = acc[mi][ni][r];
                if (ADD_BIAS) v += bias[gn];
                if (OUT_BF16)
                    ((unsigned short*)Cv)[base + gn] = f2bf_rne(v);
                else
                    ((float*)Cv)[base + gn] = v;
            }
        }
    }
}

// ---------------- launch ----------------

extern "C" void kernel_launch(void* const* d_in, const int* in_sizes, int n_in,
                              void* d_out, int out_size, void* d_ws, size_t ws_size,
                              hipStream_t stream) {
    const float* x    = (const float*)d_in[0];
    const float* V    = (const float*)d_in[1];
    const float* U    = (const float*)d_in[2];
    const float* v2   = (const float*)d_in[3];
    const float* v1   = (const float*)d_in[4];
    const float* u2   = (const float*)d_in[5];
    const float* u1   = (const float*)d_in[6];
    const float* V_R  = (const float*)d_in[7];
    const float* U_R  = (const float*)d_in[8];
    const float* v2_R = (const float*)d_in[9];
    const float* v1_R = (const float*)d_in[10];
    const float* u2_R = (const float*)d_in[11];
    const float* u1_R = (const float*)d_in[12];
    const float* bias = (const float*)d_in[13];
    float* out = (float*)d_out;

    char* ws = (char*)d_ws;
    unsigned short* Xb = (unsigned short*)ws;                                   // 8192*4096*2 = 64 MiB
    unsigned short* W1 = (unsigned short*)(ws + (size_t)67108864);              // 2048*4096*2 = 16 MiB
    unsigned short* W2 = (unsigned short*)(ws + (size_t)67108864 + 16777216);   // 4096*2048*2 = 16 MiB
    unsigned short* H  = (unsigned short*)(ws + (size_t)67108864 + 33554432);   // 8192*2048*2 = 32 MiB

    // x: 8192*4096 = 33554432 floats -> /4 = 8388608 threads
    cast_x_kernel<<<32768, 256, 0, stream>>>(x, Xb, 8388608);
    // fused weight prep: 8192 blocks W1 + 8192 blocks W2
    prep_w_kernel<<<16384, 256, 0, stream>>>(V, V_R, v2, v2_R,
                                             U, U_R, v1, v1_R, u2, u2_R, u1, u1_R,
                                             W1, W2);

    // GEMM1: H[8192,2048] = Xb @ W1^T, K=4096  -> 32x8 = 256 tiles (1/CU)
    gemm256<true, false><<<dim3(256), 512, 0, stream>>>(Xb, W1, (void*)H, nullptr,
                                                        8192, 2048, 4096, 8);
    // GEMM2: Y[8192,4096] = H @ W2^T + bias, K=2048 -> 32x16 = 512 tiles (2/CU)
    gemm256<false, true><<<dim3(512), 512, 0, stream>>>(H, W2, (void*)out, bias,
                                                        8192, 4096, 2048, 16);
}

// Round 4
// 531.908 us; speedup vs baseline: 1.1619x; 1.0092x over previous
//
#include <hip/hip_runtime.h>

// LittleBitITQSpecLinear: y = sum_b ((x*v2_b) @ sign(V_b)^T * (v1_b*u2_b)) @ sign(U_b)^T * u1_b + bias
// Folded: W1_b[s,k] = sign(V_b[s,k])*v2_b[k];  W2_b[o,s] = sign(U_b[o,s])*v1_b[s]*u2_b[s]*u1_b[o]
// => H = Xbf16 @ W1cat^T  (8192x2048, K=4096);  Y = H @ W2cat^T + bias (8192x4096, K=2048)
//
// R6: fine-grained staging (m196's lever): ONE half-tile (2 global_load_lds)
// staged EVERY phase, vmcnt(4) counted at ph4/ph8 only. R5 staged in 4-load
// lumps at ph3/4/7/8 (the exact "coarse" variant m196 measured at -7..-27%).
// Region liveness (audited against OUR read pattern): B halves of a buffer
// are read ph1(b0)+ph2(b1) -> dead after ph2; A halves ph1(a0)+ph3(a1) ->
// dead after ph3. Slot map: ph1 odd.A0, ph2 odd.A1, ph3 t2.B0, ph4 t2.B1,
// ph5 t2.A0, ph6 t2.A1, ph7 t3.B0, ph8 t3.B1 -- every overwrite is >=1
// barrier-separated phase after the region's last read (R5's proven safety
// class). Ledger: entering ph1 queue=[odd.B0,B1]; ph4 queue=12 loads,
// vmcnt(4) retires exactly the odd tile before ph5 reads it; symmetric ph8.
// Never a drain in the main loop. Also fused cast_x+prep_w into one launch.

typedef __bf16 bf16x8 __attribute__((ext_vector_type(8)));
typedef float floatx4 __attribute__((ext_vector_type(4)));

__device__ __forceinline__ unsigned short f2bf_rne(float f) {
    union { float f; unsigned u; } v; v.f = f;
    unsigned r = v.u + 0x7FFFu + ((v.u >> 16) & 1u);
    return (unsigned short)(r >> 16);
}

__device__ __forceinline__ float sgnf(float w) {
    return (float)((w > 0.f) - (w < 0.f));
}

__device__ __forceinline__ void async_copy16(const void* g, void* l) {
    __builtin_amdgcn_global_load_lds(
        (const __attribute__((address_space(1))) void*)g,
        (__attribute__((address_space(3))) void*)l, 16, 0, 0);
}

#define FENCE() asm volatile("" ::: "memory")
#define BAR() do { FENCE(); __builtin_amdgcn_s_barrier(); FENCE(); } while (0)
#define VMW(N) asm volatile("s_waitcnt vmcnt(" #N ")" ::: "memory")
#define LGKM(N) asm volatile("s_waitcnt lgkmcnt(" #N ")" ::: "memory")

// ---------------- fused prep kernel ----------------
// Blocks [0,32768): cast x -> bf16 (4 float4 elems/thread).
// Blocks [32768,40960): W1cat[s_cat][k] (2048x4096).
// Blocks [40960,49152): W2cat[o][s_cat] (4096x2048).

__global__ void prep_all_kernel(const float* __restrict__ x,
                                unsigned short* __restrict__ xb,
                                const float* __restrict__ V, const float* __restrict__ V_R,
                                const float* __restrict__ v2, const float* __restrict__ v2_R,
                                const float* __restrict__ U, const float* __restrict__ U_R,
                                const float* __restrict__ v1, const float* __restrict__ v1_R,
                                const float* __restrict__ u2, const float* __restrict__ u2_R,
                                const float* __restrict__ u1, const float* __restrict__ u1_R,
                                unsigned short* __restrict__ W1,
                                unsigned short* __restrict__ W2) {
    int bid = blockIdx.x;
    if (bid < 32768) {
        int i = bid * blockDim.x + threadIdx.x;   // 8388608 = 32768*256 exact
        float4 v = ((const float4*)x)[i];
        ushort4 o;
        o.x = f2bf_rne(v.x); o.y = f2bf_rne(v.y);
        o.z = f2bf_rne(v.z); o.w = f2bf_rne(v.w);
        ((ushort4*)xb)[i] = o;
    } else if (bid < 40960) {
        int i = (bid - 32768) * blockDim.x + threadIdx.x;  // 4 elems each
        int idx = i << 2;
        int scat = idx >> 12;
        int k = idx & 4095;
        const float* Vp; const float* sp;
        if (scat < 1024) { Vp = V + ((size_t)scat << 12); sp = v2; }
        else             { Vp = V_R + ((size_t)(scat - 1024) << 12); sp = v2_R; }
        float4 w = *(const float4*)(Vp + k);
        float4 s = *(const float4*)(sp + k);
        ushort4 o;
        o.x = f2bf_rne(sgnf(w.x) * s.x);
        o.y = f2bf_rne(sgnf(w.y) * s.y);
        o.z = f2bf_rne(sgnf(w.z) * s.z);
        o.w = f2bf_rne(sgnf(w.w) * s.w);
        ((ushort4*)W1)[i] = o;
    } else {
        int i = (bid - 40960) * blockDim.x + threadIdx.x;  // 4 elems each
        int idx = i << 2;
        int o = idx >> 11;
        int scat = idx & 2047;
        int branch = scat >> 10;
        int s = scat & 1023;
        const float* Up  = branch ? U_R  : U;
        const float* v1p = branch ? v1_R : v1;
        const float* u2p = branch ? u2_R : u2;
        float u1v = (branch ? u1_R : u1)[o];
        float4 w = *(const float4*)(Up + ((size_t)o << 10) + s);
        float4 a = *(const float4*)(v1p + s);
        float4 b = *(const float4*)(u2p + s);
        ushort4 out;
        out.x = f2bf_rne(sgnf(w.x) * a.x * b.x * u1v);
        out.y = f2bf_rne(sgnf(w.y) * a.y * b.y * u1v);
        out.z = f2bf_rne(sgnf(w.z) * a.z * b.z * u1v);
        out.w = f2bf_rne(sgnf(w.w) * a.w * b.w * u1v);
        ((ushort4*)W2)[i] = out;
    }
}

// ---------------- GEMM: C[M,N] = A[M,K] @ B[N,K]^T ----------------
// 256x256 tile, BK=64, 512 threads = 8 waves (2M x 4N), per-wave 128x64 out.
// LDS: [buf][half] 128x64 bf16 = 16 KiB per region; 2 bufs x 2 halves x (A+B)
// = 128 KiB. Wave (wm,wn) reads A-half[wm] and B-half[wn>>1] only.

template <bool OUT_BF16, bool ADD_BIAS>
__global__ __launch_bounds__(512, 2)
void gemm256(const unsigned short* __restrict__ A,
             const unsigned short* __restrict__ B,
             void* __restrict__ Cv,
             const float* __restrict__ bias,
             int M, int N, int K, int ntn) {
    (void)M;
    __shared__ __align__(16) unsigned short As[2][2][128 * 64];
    __shared__ __align__(16) unsigned short Bs[2][2][128 * 64];

    const int tid = threadIdx.x;
    const int lane = tid & 63;
    const int wave = tid >> 6;
    const int warp_m = wave >> 2;   // 0..1
    const int warp_n = wave & 3;    // 0..3

    // XCD-aware swizzle (nwg % 8 == 0 for both GEMMs -> bijective)
    const int nwg = gridDim.x;
    const int hw = blockIdx.x;
    const int swz = (hw & 7) * (nwg >> 3) + (hw >> 3);
    const int tm = swz / ntn;
    const int tn = swz - tm * ntn;
    const int m0 = tm << 8;
    const int n0 = tn << 8;

    // staging: one half-tile region = 128 rows x 64 cols = 2 global_load_lds
    // (512 threads x 16B = 64 rows per instr). Fetch-side chunk-XOR swizzle:
    // LDS[r][c8] = global[r][c8 ^ (r&7)], LDS dest linear (HW requirement).
    const int srow = tid >> 3;                          // 0..63
    const int scg8 = (((tid & 7) ^ (srow & 7)) << 3);   // swizzled chunk * 8
    const int ldst = tid << 3;                          // 0..4095 elems
    const size_t Ks = (size_t)K;

    auto stA = [&](int buf, int h, int kt) {
        const unsigned short* g = A + (size_t)(m0 + (h << 7) + srow) * Ks + (kt << 6) + scg8;
        async_copy16(g,             &As[buf][h][ldst]);
        async_copy16(g + (Ks << 6), &As[buf][h][4096 + ldst]);
    };
    auto stB = [&](int buf, int h, int kt) {
        const unsigned short* g = B + (size_t)(n0 + (h << 7) + srow) * Ks + (kt << 6) + scg8;
        async_copy16(g,             &Bs[buf][h][ldst]);
        async_copy16(g + (Ks << 6), &Bs[buf][h][4096 + ldst]);
    };

    // fragment reads (read-side swizzle matches fetch-side; proven R0/R5)
    const int fm = lane & 15;
    const int cgl = lane >> 4;                // 0..3
    const int key = fm & 7;
    const int ok0 = ((cgl ^ key) << 3);       // elem offset, k-slice 0
    const int ok1 = (((4 | cgl) ^ key) << 3); // elem offset, k-slice 1

    auto lda = [&](bf16x8 (&dst)[4][2], int buf, int mh) {
        const unsigned short* base = &As[buf][warp_m][0];
#pragma unroll
        for (int mi = 0; mi < 4; ++mi) {
            const unsigned short* p = base + (((mh << 6) + (mi << 4) + fm) << 6);
            dst[mi][0] = *(const bf16x8*)(p + ok0);
            dst[mi][1] = *(const bf16x8*)(p + ok1);
        }
    };
    auto ldb = [&](bf16x8 (&dst)[2][2], int buf, int nh) {
        const unsigned short* base = &Bs[buf][warp_n >> 1][0];
#pragma unroll
        for (int ni = 0; ni < 2; ++ni) {
            const unsigned short* p = base + ((((warp_n & 1) << 6) + (nh << 5) + (ni << 4) + fm) << 6);
            dst[ni][0] = *(const bf16x8*)(p + ok0);
            dst[ni][1] = *(const bf16x8*)(p + ok1);
        }
    };

    floatx4 acc[8][4];
#pragma unroll
    for (int i = 0; i < 8; ++i)
#pragma unroll
        for (int j = 0; j < 4; ++j)
#pragma unroll
            for (int r = 0; r < 4; ++r) acc[i][j][r] = 0.f;

    bf16x8 a0[4][2], a1[4][2], b0[2][2], b1[2][2];

#define MMAQ(aS, bS, MH, NH) do { \
    __builtin_amdgcn_s_setprio(1); \
    _Pragma("unroll") \
    for (int mi_ = 0; mi_ < 4; ++mi_) { \
      _Pragma("unroll") \
      for (int ni_ = 0; ni_ < 2; ++ni_) { \
        acc[(MH)*4 + mi_][(NH)*2 + ni_] = __builtin_amdgcn_mfma_f32_16x16x32_bf16( \
            aS[mi_][0], bS[ni_][0], acc[(MH)*4 + mi_][(NH)*2 + ni_], 0, 0, 0); \
        acc[(MH)*4 + mi_][(NH)*2 + ni_] = __builtin_amdgcn_mfma_f32_16x16x32_bf16( \
            aS[mi_][1], bS[ni_][1], acc[(MH)*4 + mi_][(NH)*2 + ni_], 0, 0, 0); \
      } } \
    __builtin_amdgcn_s_setprio(0); \
  } while (0)

    // ---- prologue: tile0 (buf0, 8 loads) + tile1 {B0,B1} (4 loads).
    // VMW(4) retires tile0 -> resident; queue = [t1.B0, t1.B1] (invariant).
    stB(0, 0, 0); stB(0, 1, 0); stA(0, 0, 0); stA(0, 1, 0);
    stB(1, 0, 1); stB(1, 1, 1);
    VMW(4);
    BAR();

    const int NT = K >> 6;
    for (int i = 0; i < (NT >> 1) - 1; ++i) {
        const int t1k = 2 * i + 1, t2k = 2 * i + 2, t3k = 2 * i + 3;
        // ph1: even tile (buf0) Q00; stage odd.A0 (buf1.A0 dead since prev ph7)
        lda(a0, 0, 0); ldb(b0, 0, 0);
        stA(1, 0, t1k);
        LGKM(8);
        BAR(); LGKM(0);
        MMAQ(a0, b0, 0, 0);
        BAR();
        // ph2: Q01; stage odd.A1 (buf1.A1 dead since prev ph7)
        ldb(b1, 0, 1);
        stA(1, 1, t1k);
        BAR(); LGKM(0);
        MMAQ(a0, b1, 0, 1);
        BAR();
        // ph3: Q11; stage t2.B0 (buf0.B0 dead after ph2: b0@ph1, b1@ph2)
        lda(a1, 0, 1);
        stB(0, 0, t2k);
        BAR(); LGKM(0);
        MMAQ(a1, b1, 1, 1);
        BAR();
        // ph4: Q10; stage t2.B1; VMW(4): queue=[odd.B0,B1,A0,A1,t2.B0,B1]
        // -> retires exactly the odd tile before ph5 reads it.
        stB(0, 1, t2k);
        VMW(4);
        BAR();
        MMAQ(a1, b0, 1, 0);
        BAR();
        // ph5: odd tile (buf1) Q00; stage t2.A0 (buf0.A0 dead after ph3)
        lda(a0, 1, 0); ldb(b0, 1, 0);
        stA(0, 0, t2k);
        LGKM(8);
        BAR(); LGKM(0);
        MMAQ(a0, b0, 0, 0);
        BAR();
        // ph6: Q01; stage t2.A1 (buf0.A1 dead after ph3)
        ldb(b1, 1, 1);
        stA(0, 1, t2k);
        BAR(); LGKM(0);
        MMAQ(a0, b1, 0, 1);
        BAR();
        // ph7: Q11; stage t3.B0 (buf1.B0 dead after ph6: b0@ph5, b1@ph6)
        lda(a1, 1, 1);
        stB(1, 0, t3k);
        BAR(); LGKM(0);
        MMAQ(a1, b1, 1, 1);
        BAR();
        // ph8: Q10; stage t3.B1; VMW(4) retires t2 before next ph1 reads it.
        stB(1, 1, t3k);
        VMW(4);
        BAR();
        MMAQ(a1, b0, 1, 0);
        BAR();
    }
    // ---- epilogue: tiles NT-2 (buf0), NT-1 (buf1); queue=[tL.B0,B1].
    {
        const int tLk = NT - 1;
        lda(a0, 0, 0); ldb(b0, 0, 0);
        stA(1, 0, tLk);
        LGKM(8);
        BAR(); LGKM(0);
        MMAQ(a0, b0, 0, 0);
        BAR();
        ldb(b1, 0, 1);
        stA(1, 1, tLk);
        BAR(); LGKM(0);
        MMAQ(a0, b1, 0, 1);
        BAR();
        lda(a1, 0, 1);
        BAR(); LGKM(0);
        MMAQ(a1, b1, 1, 1);
        BAR();
        VMW(0);          // retire tL's 4 halves (oldest issued 6+ phases ago)
        BAR();
        MMAQ(a1, b0, 1, 0);
        BAR();
        // final tile NT-1 (buf1): fully resident; no further LDS writes.
        lda(a0, 1, 0); ldb(b0, 1, 0);
        ldb(b1, 1, 1); lda(a1, 1, 1);
        MMAQ(a0, b0, 0, 0);
        MMAQ(a0, b1, 0, 1);
        MMAQ(a1, b1, 1, 1);
        MMAQ(a1, b0, 1, 0);
    }
#undef MMAQ

    // epilogue C-write: C/D layout col=lane&15, row=(lane>>4)*4+reg [m89]
    const int rq = (lane >> 4) << 2;
    const int col = lane & 15;
#pragma unroll
    for (int mi = 0; mi < 8; ++mi) {
#pragma unroll
        for (int r = 0; r < 4; ++r) {
            const int gm = m0 + (warp_m << 7) + (mi << 4) + rq + r;
            const size_t base = (size_t)gm * (size_t)N;
#pragma unroll
            for (int ni = 0; ni < 4; ++ni) {
                const int gn = n0 + (warp_n << 6) + (ni << 4) + col;
                float v = acc[mi][ni][r];
                if (ADD_BIAS) v += bias[gn];
                if (OUT_BF16)
                    ((unsigned short*)Cv)[base + gn] = f2bf_rne(v);
                else
                    ((float*)Cv)[base + gn] = v;
            }
        }
    }
}

// ---------------- launch ----------------

extern "C" void kernel_launch(void* const* d_in, const int* in_sizes, int n_in,
                              void* d_out, int out_size, void* d_ws, size_t ws_size,
                              hipStream_t stream) {
    const float* x    = (const float*)d_in[0];
    const float* V    = (const float*)d_in[1];
    const float* U    = (const float*)d_in[2];
    const float* v2   = (const float*)d_in[3];
    const float* v1   = (const float*)d_in[4];
    const float* u2   = (const float*)d_in[5];
    const float* u1   = (const float*)d_in[6];
    const float* V_R  = (const float*)d_in[7];
    const float* U_R  = (const float*)d_in[8];
    const float* v2_R = (const float*)d_in[9];
    const float* v1_R = (const float*)d_in[10];
    const float* u2_R = (const float*)d_in[11];
    const float* u1_R = (const float*)d_in[12];
    const float* bias = (const float*)d_in[13];
    float* out = (float*)d_out;

    char* ws = (char*)d_ws;
    unsigned short* Xb = (unsigned short*)ws;                                   // 8192*4096*2 = 64 MiB
    unsigned short* W1 = (unsigned short*)(ws + (size_t)67108864);              // 2048*4096*2 = 16 MiB
    unsigned short* W2 = (unsigned short*)(ws + (size_t)67108864 + 16777216);   // 4096*2048*2 = 16 MiB
    unsigned short* H  = (unsigned short*)(ws + (size_t)67108864 + 33554432);   // 8192*2048*2 = 32 MiB

    // fused prep: 32768 cast blocks + 8192 W1 blocks + 8192 W2 blocks
    prep_all_kernel<<<49152, 256, 0, stream>>>(x, Xb, V, V_R, v2, v2_R,
                                               U, U_R, v1, v1_R, u2, u2_R, u1, u1_R,
                                               W1, W2);

    // GEMM1: H[8192,2048] = Xb @ W1^T, K=4096  -> 32x8 = 256 tiles (1/CU)
    gemm256<true, false><<<dim3(256), 512, 0, stream>>>(Xb, W1, (void*)H, nullptr,
                                                        8192, 2048, 4096, 8);
    // GEMM2: Y[8192,4096] = H @ W2^T + bias, K=2048 -> 32x16 = 512 tiles (2/CU)
    gemm256<false, true><<<dim3(512), 512, 0, stream>>>(H, W2, (void*)out, bias,
                                                        8192, 4096, 2048, 16);
}